// Round 5
// baseline (1068.913 us; speedup 1.0000x reference)
//
#include <hip/hip_runtime.h>
#include <math.h>

#define HORIZON 15
#define PAD 7
#define CIN 48
#define C2 12
#define LAT 6
#define EPS 1e-5f
#define NREP 16
#define KA 720
#define KSTEPS 23           // ceil(720/32); k in [720,736) is zero-padded in B

typedef __bf16 bf16x8 __attribute__((ext_vector_type(8)));
typedef float f32x4 __attribute__((ext_vector_type(4)));
typedef unsigned short ushort8v __attribute__((ext_vector_type(8)));
typedef unsigned short ushortT;

// bf16 split: v ~= hi + lo with hi = bf16(v), lo = bf16(v - hi)
__device__ inline void bfsplit(float v, ushortT& h, ushortT& l) {
    __bf16 bh = (__bf16)v;
    float fh = (float)bh;
    __bf16 bl = (__bf16)(v - fh);
    h = __builtin_bit_cast(ushortT, bh);
    l = __builtin_bit_cast(ushortT, bl);
}

__device__ inline float fast_elu(float h) {
    return h > 0.f ? h : __expf(h) - 1.f;
}

// Banded dense W values (zero-padded to n,k grids)
__device__ inline float w1_band(const float* __restrict__ w1, int n, int k) {
    if (n >= 720 || k >= 720) return 0.f;
    int l = n / 48, co = n % 48, ci = k / 15, t = k % 15;
    int d = t - l;
    return (d >= -PAD && d <= PAD) ? w1[(co * CIN + ci) * HORIZON + (d + PAD)] : 0.f;
}
__device__ inline float w2_band(const float* __restrict__ w2, int n, int k) {
    if (n >= 180 || k >= 720) return 0.f;
    int l = n / 12, co = n % 12, t = k / 48, ci = k % 48;
    int d = t - l;
    return (d >= -PAD && d <= PAD) ? w2[(co * CIN + ci) * HORIZON + (d + PAD)] : 0.f;
}

// ---------------------------------------------------------------------------
// prep: weights swizzled to MFMA-fragment-sequential order:
//   Bsw[((nfrag*KSTEPS + ks)*64 + lane)*8 + j] = W[nfrag*16 + (lane&15)]
//                                                 [ks*32 + (lane>>4)*8 + j]
// -> a B fragment load is one coalesced 16B/lane read, no LDS needed.
// W1: 48 nfrags (768 cols padded), W2: 12 nfrags (192 cols padded).
// Also: w3t [ci][k][co] for tail, rfft trig table.
// ---------------------------------------------------------------------------
#define N1SW (48 * KSTEPS * 512)   // 565248
#define N2SW (12 * KSTEPS * 512)   // 141312

__global__ void prep_kernel(const float* __restrict__ w1, const float* __restrict__ w2,
                            const float* __restrict__ w3,
                            ushortT* __restrict__ w1swh, ushortT* __restrict__ w1swl,
                            ushortT* __restrict__ w2swh, ushortT* __restrict__ w2swl,
                            float* __restrict__ w3t, float* __restrict__ trig) {
    int idx = blockIdx.x * blockDim.x + threadIdx.x;
    const int n3 = C2 * HORIZON * LAT;
    if (idx < N1SW) {
        int j = idx & 7, lane = (idx >> 3) & 63;
        int ks = (idx >> 9) % KSTEPS, nb = idx / (KSTEPS * 512);
        int n = nb * 16 + (lane & 15);
        int k = ks * 32 + (lane >> 4) * 8 + j;
        ushortT h, lo; bfsplit(w1_band(w1, n, k), h, lo);
        w1swh[idx] = h; w1swl[idx] = lo;
    } else if (idx < N1SW + N2SW) {
        int e = idx - N1SW;
        int j = e & 7, lane = (e >> 3) & 63;
        int ks = (e >> 9) % KSTEPS, nb = e / (KSTEPS * 512);
        int n = nb * 16 + (lane & 15);
        int k = ks * 32 + (lane >> 4) * 8 + j;
        ushortT h, lo; bfsplit(w2_band(w2, n, k), h, lo);
        w2swh[e] = h; w2swl[e] = lo;
    } else if (idx < N1SW + N2SW + n3) {
        int j = idx - N1SW - N2SW;
        int co = j % LAT; int r = j / LAT; int k = r % HORIZON; int ci = r / HORIZON;
        w3t[j] = w3[(co * C2 + ci) * HORIZON + k];
    } else if (idx < N1SW + N2SW + n3 + 7 * HORIZON) {
        int j = idx - (N1SW + N2SW + n3);
        int l = j % HORIZON; int f = j / HORIZON + 1;
        double ang = -2.0 * 3.14159265358979323846 * (double)(f * l) / 15.0;
        trig[j * 2]     = (float)cos(ang);
        trig[j * 2 + 1] = (float)sin(ang);
    }
}

// ---------------------------------------------------------------------------
// Barrier-free, LDS-free split-precision MFMA GEMM.
// Y[M][nreal] = A[M][720] * W^T, acc = Ah*Bh + Al*Bh + Ah*Bl.
// Per-wave tile: 32 rows (2 m-frags) x NFRAG*16 cols. Block = 4 waves = 128 rows.
// A: direct float4 global loads (+ optional fused BN+ELU), in-register split.
// B: direct 16B loads from fragment-swizzled arrays (L2-resident).
// No __syncthreads in the K-loop -> no vmcnt(0) drain; compiler pipelines.
// ---------------------------------------------------------------------------
template <int NFRAG, int CSTAT, bool FUSE_BN>
__global__ __launch_bounds__(256, 2)
void gemm_direct(const float* __restrict__ A,
                 const ushortT* __restrict__ Bh, const ushortT* __restrict__ Bl,
                 const float* __restrict__ bnp,
                 float* __restrict__ Y, int ldy, int nreal,
                 float* __restrict__ stats) {
    __shared__ float s_stats[2 * CSTAT];
    const int tid = threadIdx.x;
    const int w = tid >> 6, lane = tid & 63;
    const int lr = lane & 15, lq = lane >> 4;
    if (tid < 2 * CSTAT) s_stats[tid] = 0.f;
    __syncthreads();

    const long m_base = (long)blockIdx.x * 128 + w * 32;
    const int fg0 = blockIdx.y * NFRAG;
    const int n0 = fg0 * 16;

    f32x4 acc[2][NFRAG];
#pragma unroll
    for (int i = 0; i < 2; i++)
#pragma unroll
        for (int j = 0; j < NFRAG; j++) acc[i][j] = (f32x4){0.f, 0.f, 0.f, 0.f};

    for (int ks = 0; ks < KSTEPS; ks++) {
        const int k0 = ks * 32;
        const int kq = k0 + lq * 8;
        const bool kv = kq < KA;   // k-octets are 8-aligned; 720 % 8 == 0

        // ---- A fragments: direct load + (BN+ELU) + in-register split ----
        bf16x8 ah[2], al[2];
#pragma unroll
        for (int fr = 0; fr < 2; fr++) {
            ushort8v vh = (ushort8v)0, vl = (ushort8v)0;
            if (kv) {
                const float4* p = (const float4*)(A + (m_base + fr * 16 + lr) * (long)KA + kq);
                float4 u0 = p[0], u1 = p[1];
                float f[8] = {u0.x, u0.y, u0.z, u0.w, u1.x, u1.y, u1.z, u1.w};
                if (FUSE_BN) {
                    int cb = kq % 48;   // octets never straddle a 48-boundary
#pragma unroll
                    for (int jj = 0; jj < 8; jj++)
                        f[jj] = fast_elu(fmaf(f[jj], bnp[(cb + jj) * 2], bnp[(cb + jj) * 2 + 1]));
                }
#pragma unroll
                for (int jj = 0; jj < 8; jj++) {
                    ushortT hh, ll; bfsplit(f[jj], hh, ll);
                    vh[jj] = hh; vl[jj] = ll;
                }
            }
            ah[fr] = __builtin_bit_cast(bf16x8, vh);
            al[fr] = __builtin_bit_cast(bf16x8, vl);
        }

        // ---- B fragments direct from swizzled global + MFMA ----
#pragma unroll
        for (int fc = 0; fc < NFRAG; fc++) {
            const long boff = ((long)(fg0 + fc) * KSTEPS + ks) * 512 + lane * 8;
            bf16x8 bhf = *(const bf16x8*)(Bh + boff);
            bf16x8 blf = *(const bf16x8*)(Bl + boff);
#pragma unroll
            for (int fr = 0; fr < 2; fr++) {
                acc[fr][fc] = __builtin_amdgcn_mfma_f32_16x16x32_bf16(ah[fr], bhf, acc[fr][fc], 0, 0, 0);
                acc[fr][fc] = __builtin_amdgcn_mfma_f32_16x16x32_bf16(al[fr], bhf, acc[fr][fc], 0, 0, 0);
                acc[fr][fc] = __builtin_amdgcn_mfma_f32_16x16x32_bf16(ah[fr], blf, acc[fr][fc], 0, 0, 0);
            }
        }
    }

    // ---- epilogue: store + per-channel stats (PLANAR layout) ----
    // C/D layout: col = lane&15, row = (lane>>4)*4 + reg
    float ps[3] = {0.f, 0.f, 0.f}, qs[3] = {0.f, 0.f, 0.f};
#pragma unroll
    for (int fc = 0; fc < NFRAG; fc++) {
        int col = n0 + fc * 16 + lr;
        int j = fc % 3;
#pragma unroll
        for (int fr = 0; fr < 2; fr++) {
#pragma unroll
            for (int r = 0; r < 4; r++) {
                float v = acc[fr][fc][r];
                long row = m_base + fr * 16 + lq * 4 + r;
                if (col < nreal) Y[row * (long)ldy + col] = v;
                ps[j] += v;
                qs[j] = fmaf(v, v, qs[j]);
            }
        }
    }
#pragma unroll
    for (int j = 0; j < 3; j++) {
        int c = (lr + 16 * j) % CSTAT;
        atomicAdd(&s_stats[c], ps[j]);
        atomicAdd(&s_stats[CSTAT + c], qs[j]);
    }
    __syncthreads();
    if (tid < 2 * CSTAT)
        atomicAdd(&stats[(blockIdx.x & (NREP - 1)) * 2 * CSTAT + tid], s_stats[tid]);
}

// ---------------------------------------------------------------------------
// finalize BN: planar stats [sum[0..C-1], sumsq[0..C-1]] per replica
// ---------------------------------------------------------------------------
__global__ void finalize_bn(const float* __restrict__ stats, const float* __restrict__ g,
                            const float* __restrict__ be, float* __restrict__ bn,
                            int C, float invN) {
    int c = threadIdx.x;
    if (c >= C) return;
    float s1 = 0.f, s2 = 0.f;
    for (int r = 0; r < NREP; r++) { s1 += stats[r * 2 * C + c]; s2 += stats[r * 2 * C + C + c]; }
    float m   = s1 * invN;
    float var = s2 * invN - m * m;
    float sc  = g[c] * rsqrtf(var + EPS);
    bn[c * 2]     = sc;
    bn[c * 2 + 1] = fmaf(-m, sc, be[c]);
}

// ---------------------------------------------------------------------------
// in-place BN+ELU on y2 [B][15][12] (C=12; float4 ok: c0 in {0,4,8})
// ---------------------------------------------------------------------------
__global__ void bn_act_kernel(float* __restrict__ y, const float* __restrict__ bn, long n4) {
    long i = (long)blockIdx.x * 256 + threadIdx.x;
    if (i >= n4) return;
    float4 v = ((float4*)y)[i];
    int c0 = (int)((i * 4) % 12);
    v.x = fast_elu(fmaf(v.x, bn[c0 * 2],       bn[c0 * 2 + 1]));
    v.y = fast_elu(fmaf(v.y, bn[(c0 + 1) * 2], bn[(c0 + 1) * 2 + 1]));
    v.z = fast_elu(fmaf(v.z, bn[(c0 + 2) * 2], bn[(c0 + 2) * 2 + 1]));
    v.w = fast_elu(fmaf(v.w, bn[(c0 + 3) * 2], bn[(c0 + 3) * 2 + 1]));
    ((float4*)y)[i] = v;
}

// ---------------------------------------------------------------------------
// tail: conv3 (+b3) on pre-activated h2 -> rfft stats + phase linear
// ---------------------------------------------------------------------------
__global__ __launch_bounds__(256) void tail_kernel(const float* __restrict__ h2,
                                                   const float* __restrict__ w3t,
                                                   const float* __restrict__ b3,
                                                   const float* __restrict__ pw,
                                                   const float* __restrict__ trig,
                                                   float* __restrict__ out,
                                                   float* __restrict__ vout,
                                                   float* __restrict__ stats) {
    __shared__ float s_sum[2 * LAT];
    __shared__ float s_sq[2 * LAT];
    int t = threadIdx.x;
    if (t < 2 * LAT) { s_sum[t] = 0.f; s_sq[t] = 0.f; }
    __syncthreads();

    int id = blockIdx.x * 256 + t;
    int co = id % LAT;
    long b = id / LAT;
    const float* xr = h2 + b * (long)(C2 * HORIZON);

    float acc[HORIZON];
#pragma unroll
    for (int l = 0; l < HORIZON; l++) acc[l] = b3[co];

    for (int ci = 0; ci < C2; ci++) {
        float xv[HORIZON];
#pragma unroll
        for (int tt = 0; tt < HORIZON; tt++) xv[tt] = xr[tt * C2 + ci];
        float wv[HORIZON];
#pragma unroll
        for (int k = 0; k < HORIZON; k++) wv[k] = w3t[(ci * HORIZON + k) * LAT + co];
#pragma unroll
        for (int tt = 0; tt < HORIZON; tt++) {
            const int lo = (tt - PAD) > 0 ? (tt - PAD) : 0;
            const int hi = (tt + PAD) < (HORIZON - 1) ? (tt + PAD) : (HORIZON - 1);
#pragma unroll
            for (int l = lo; l <= hi; l++)
                acc[l] = fmaf(xv[tt], wv[tt - l + PAD], acc[l]);
        }
    }

    float ssum = 0.f;
#pragma unroll
    for (int l = 0; l < HORIZON; l++) ssum += acc[l];
    float b_off = ssum * (1.f / 15.f);

    float psum = 0.f, fnum = 0.f;
#pragma unroll
    for (int j = 0; j < 7; j++) {
        float re = 0.f, im = 0.f;
#pragma unroll
        for (int l = 0; l < HORIZON; l++) {
            float c = trig[(j * HORIZON + l) * 2];
            float s = trig[(j * HORIZON + l) * 2 + 1];
            re = fmaf(acc[l], c, re);
            im = fmaf(acc[l], s, im);
        }
        float p = fmaf(re, re, im * im);
        psum += p;
        fnum = fmaf((float)(j + 1), p, fnum);
    }
    float f = fnum / psum;
    float a = 2.f * sqrtf(psum) * (1.f / 15.f);

    float* orow = out + b * 24;
    orow[6 + co]  = f;
    orow[12 + co] = a;
    orow[18 + co] = b_off;

    float v0 = 0.f, v1 = 0.f;
#pragma unroll
    for (int l = 0; l < HORIZON; l++) {
        v0 = fmaf(acc[l], pw[(co * 2 + 0) * HORIZON + l], v0);
        v1 = fmaf(acc[l], pw[(co * 2 + 1) * HORIZON + l], v1);
    }
    vout[b * 12 + co * 2]     = v0;
    vout[b * 12 + co * 2 + 1] = v1;
    atomicAdd(&s_sum[co * 2], v0);
    atomicAdd(&s_sq[co * 2], v0 * v0);
    atomicAdd(&s_sum[co * 2 + 1], v1);
    atomicAdd(&s_sq[co * 2 + 1], v1 * v1);

    __syncthreads();
    float* st = stats + (blockIdx.x & (NREP - 1)) * 2 * (2 * LAT);
    if (t < 2 * LAT) {
        atomicAdd(&st[t], s_sum[t]);
        atomicAdd(&st[2 * LAT + t], s_sq[t]);
    }
}

// ---------------------------------------------------------------------------
__global__ void phase_kernel(const float* __restrict__ v, const float* __restrict__ bnP,
                             float* __restrict__ out, long B) {
    long b = (long)blockIdx.x * 256 + threadIdx.x;
    if (b >= B) return;
#pragma unroll
    for (int co = 0; co < LAT; co++) {
        float v0 = v[b * 12 + co * 2];
        float v1 = v[b * 12 + co * 2 + 1];
        int c0 = co * 2, c1 = co * 2 + 1;
        v0 = fmaf(v0, bnP[c0 * 2], bnP[c0 * 2 + 1]);
        v1 = fmaf(v1, bnP[c1 * 2], bnP[c1 * 2 + 1]);
        out[b * 24 + co] = atan2f(v1, v0) * 0.15915494309189535f;
    }
}

// ---------------------------------------------------------------------------
extern "C" void kernel_launch(void* const* d_in, const int* in_sizes, int n_in,
                              void* d_out, int out_size, void* d_ws, size_t ws_size,
                              hipStream_t stream) {
    const float* x   = (const float*)d_in[0];
    const float* w1  = (const float*)d_in[1];
    const float* g1  = (const float*)d_in[3];
    const float* be1 = (const float*)d_in[4];
    const float* w2  = (const float*)d_in[5];
    const float* g2  = (const float*)d_in[7];
    const float* be2 = (const float*)d_in[8];
    const float* w3  = (const float*)d_in[9];
    const float* b3  = (const float*)d_in[10];
    const float* pw  = (const float*)d_in[11];
    const float* pg  = (const float*)d_in[13];
    const float* pbe = (const float*)d_in[14];
    float* out = (float*)d_out;

    long B = (long)in_sizes[0] / (CIN * HORIZON);   // 65536

    // swizzled bf16 weights first (16B-aligned, frag-sequential)
    ushortT* w1swh = (ushortT*)d_ws;          // N1SW
    ushortT* w1swl = w1swh + N1SW;
    ushortT* w2swh = w1swl + N1SW;            // N2SW
    ushortT* w2swl = w2swh + N2SW;
    float* y1 = (float*)(w2swl + N2SW);       // B*720 (16B-aligned: N1SW/N2SW even)
    float* y2 = y1 + B * 720;                 // B*180
    float* vv = y2 + B * 180;                 // B*12
    float* stats1 = vv + B * 12;              // NREP*96
    float* stats2 = stats1 + NREP * 96;       // NREP*24
    float* statsP = stats2 + NREP * 24;       // NREP*24
    float* bn1 = statsP + NREP * 24;          // 96
    float* bn2 = bn1 + 96;                    // 24
    float* bnP = bn2 + 24;                    // 24
    float* w3t = bnP + 24;                    // 1080
    float* trig = w3t + C2 * HORIZON * LAT;   // 210

    hipMemsetAsync(stats1, 0, NREP * (96 + 24 + 24) * sizeof(float), stream);

    const int prep_total = N1SW + N2SW + C2 * HORIZON * LAT + 7 * HORIZON;
    prep_kernel<<<(prep_total + 255) / 256, 256, 0, stream>>>(
        w1, w2, w3, w1swh, w1swl, w2swh, w2swl, w3t, trig);

    // GEMM1: x [B][720] -> y1 [B][720], stats1
    gemm_direct<15, 48, false><<<dim3((int)(B / 128), 3), 256, 0, stream>>>(
        x, w1swh, w1swl, nullptr, y1, 720, 720, stats1);
    finalize_bn<<<1, 64, 0, stream>>>(stats1, g1, be1, bn1, CIN, 1.f / (float)(B * HORIZON));

    // GEMM2: BN1+ELU fused in A-path; y1 -> y2 [B][180], stats2
    gemm_direct<12, 12, true><<<dim3((int)(B / 128), 1), 256, 0, stream>>>(
        y1, w2swh, w2swl, bn1, y2, 180, 180, stats2);
    finalize_bn<<<1, 64, 0, stream>>>(stats2, g2, be2, bn2, C2, 1.f / (float)(B * HORIZON));

    // BN2+ELU in-place on y2, then tail (no transcendentals inside)
    bn_act_kernel<<<(int)(B * 180 / 4 / 256), 256, 0, stream>>>(y2, bn2, B * 180 / 4);
    tail_kernel<<<(int)(B * LAT / 256), 256, 0, stream>>>(y2, w3t, b3, pw, trig, out, vv, statsP);
    finalize_bn<<<1, 64, 0, stream>>>(statsP, pg, pbe, bnP, 2 * LAT, 1.f / (float)B);

    phase_kernel<<<(int)((B + 255) / 256), 256, 0, stream>>>(vv, bnP, out, B);
}